// Round 3
// baseline (1082.975 us; speedup 1.0000x reference)
//
#include <hip/hip_runtime.h>

#define N_NODES 100000
#define N_EDGES 1600000
#define IN_F 128
#define OUT_F 64
#define LN_EPS 1e-5f

#define BUCKET_SHIFT 7                       // 128 nodes per bucket
#define NB ((N_NODES + 127) >> BUCKET_SHIFT) // 782

#define PART_BLOCKS 256
#define PART_THREADS 1024
#define PART_CHUNK ((N_EDGES + PART_BLOCKS - 1) / PART_BLOCKS)  // 6250

__device__ __forceinline__ unsigned short f2bf(float f) {
  unsigned int u = __float_as_uint(f);
  unsigned int r = (u + 0x7FFFu + ((u >> 16) & 1u)) >> 16;
  return (unsigned short)r;
}
__device__ __forceinline__ float bf2f(unsigned short h) {
  return __uint_as_float((unsigned int)h << 16);
}

// ---------------------------------------------------------------------------
// Kernel 1: dual GEMM.
//   blocks [0,512):    support = x @ W           -> bf16 [N,64]
//   blocks [512,1024): resid   = x @ res_w.T + res_b -> f32 [N,64]
// Wave computes one node row; weight column/row cached in 128 VGPRs; x rows
// staged in LDS, read as broadcast float4.
// ---------------------------------------------------------------------------
__global__ __launch_bounds__(256) void dual_gemm(
    const float* __restrict__ x, const float* __restrict__ W,
    const float* __restrict__ res_w, const float* __restrict__ res_b,
    unsigned short* __restrict__ support, float* __restrict__ resid) {
  __shared__ float xl[4 * IN_F];
  const int o = threadIdx.x & 63;
  const int wid = threadIdx.x >> 6;
  const int half = 512;
  const bool do_resid = blockIdx.x >= half;
  const int b0 = do_resid ? (int)blockIdx.x - half : (int)blockIdx.x;

  float wc[IN_F];
  if (do_resid) {
    const float4* rwrow = (const float4*)(res_w + (size_t)o * IN_F);
#pragma unroll
    for (int k4 = 0; k4 < IN_F / 4; ++k4) {
      float4 t = rwrow[k4];
      wc[k4 * 4 + 0] = t.x; wc[k4 * 4 + 1] = t.y;
      wc[k4 * 4 + 2] = t.z; wc[k4 * 4 + 3] = t.w;
    }
  } else {
#pragma unroll
    for (int k = 0; k < IN_F; ++k) wc[k] = W[k * OUT_F + o];
  }
  const float rb = do_resid ? res_b[o] : 0.f;

  const int ngroups = N_NODES / 4;  // 25000 exact
  for (int g = b0; g < ngroups; g += half) {
    __syncthreads();
    if (threadIdx.x < 128) {
      ((float4*)xl)[threadIdx.x] =
          ((const float4*)(x + (size_t)g * 4 * IN_F))[threadIdx.x];
    }
    __syncthreads();

    const float4* xr = (const float4*)(xl + wid * IN_F);
    float acc = 0.f;
#pragma unroll
    for (int k4 = 0; k4 < IN_F / 4; ++k4) {
      float4 xv = xr[k4];
      acc = fmaf(xv.x, wc[k4 * 4 + 0], acc);
      acc = fmaf(xv.y, wc[k4 * 4 + 1], acc);
      acc = fmaf(xv.z, wc[k4 * 4 + 2], acc);
      acc = fmaf(xv.w, wc[k4 * 4 + 3], acc);
    }
    const size_t idx = ((size_t)g * 4 + wid) * OUT_F + o;
    if (do_resid) resid[idx] = acc + rb;
    else          support[idx] = f2bf(acc);
  }
}

// ---------------------------------------------------------------------------
// Kernel 2: bucket histogram (LDS-aggregated; one global atomic per
// (block,bucket)).
// ---------------------------------------------------------------------------
__global__ __launch_bounds__(256) void bucket_hist(const int* __restrict__ edst,
                                                   int* __restrict__ bcnt) {
  __shared__ int lc[NB];
  for (int i = threadIdx.x; i < NB; i += 256) lc[i] = 0;
  __syncthreads();
  const int stride = gridDim.x * 256;
  for (int i = blockIdx.x * 256 + threadIdx.x; i < N_EDGES; i += stride)
    atomicAdd(&lc[edst[i] >> BUCKET_SHIFT], 1);
  __syncthreads();
  for (int i = threadIdx.x; i < NB; i += 256)
    if (lc[i]) atomicAdd(&bcnt[i], lc[i]);
}

// ---------------------------------------------------------------------------
// Kernel 3: exclusive scan over NB=782 bucket counts (single 1024-thread
// block), producing bucket start offsets (bstart) and the mutable cursor
// array (gcur) consumed by partition.
// ---------------------------------------------------------------------------
__global__ __launch_bounds__(1024) void bucket_scan(
    const int* __restrict__ bcnt, int* __restrict__ gcur,
    int* __restrict__ bstart) {
  __shared__ int sh[1024];
  const int t = threadIdx.x;
  const int v = (t < NB) ? bcnt[t] : 0;
  sh[t] = v;
  __syncthreads();
  for (int off = 1; off < 1024; off <<= 1) {
    int tm = (t >= off) ? sh[t - off] : 0;
    __syncthreads();
    sh[t] += tm;
    __syncthreads();
  }
  if (t < NB) {
    const int ex = sh[t] - v;
    gcur[t] = ex;
    bstart[t] = ex;
  }
  if (t == 0) bstart[NB] = N_EDGES;
}

// ---------------------------------------------------------------------------
// Kernel 4: block-aggregated partition. Each block counts its chunk per
// bucket in LDS, reserves a contiguous range per bucket with ONE global
// atomic, then scatters its edges contiguously -> full-line writebacks.
// part[] entry: (src, w_bits, dst, 0)
// ---------------------------------------------------------------------------
__global__ __launch_bounds__(PART_THREADS) void partition(
    const int* __restrict__ esrc, const int* __restrict__ edst,
    const float* __restrict__ ew, int* __restrict__ gcur,
    int4* __restrict__ part) {
  __shared__ int lcnt[NB];
  __shared__ int lpos[NB];
  const int t = threadIdx.x;
  for (int i = t; i < NB; i += PART_THREADS) lcnt[i] = 0;
  __syncthreads();
  const int beg = blockIdx.x * PART_CHUNK;
  const int end = min(beg + PART_CHUNK, N_EDGES);
  for (int i = beg + t; i < end; i += PART_THREADS)
    atomicAdd(&lcnt[edst[i] >> BUCKET_SHIFT], 1);
  __syncthreads();
  for (int i = t; i < NB; i += PART_THREADS)
    lpos[i] = lcnt[i] ? atomicAdd(&gcur[i], lcnt[i]) : 0;
  __syncthreads();
  for (int i = beg + t; i < end; i += PART_THREADS) {
    const int d = edst[i];
    const int p = atomicAdd(&lpos[d >> BUCKET_SHIFT], 1);
    part[p] = make_int4(esrc[i], __float_as_int(ew[i]), d, 0);
  }
}

// ---------------------------------------------------------------------------
// Kernel 5: fused bucket accumulate + finalize. One block per bucket.
// Accumulate w_e * support[src] into a 32 KB LDS tile (128 nodes x 64 f32)
// via LDS float atomics; then bias + LN(64) + ReLU + resid, single coalesced
// store of the final output. lane = feature.
// ---------------------------------------------------------------------------
__global__ __launch_bounds__(512) void bucket_accum(
    const unsigned short* __restrict__ support, const int4* __restrict__ part,
    const int* __restrict__ bstart, const float* __restrict__ resid,
    const float* __restrict__ bias, const float* __restrict__ gamma,
    const float* __restrict__ beta, float* __restrict__ out) {
  __shared__ float acc[128 * OUT_F];  // 32 KB
  const int o = threadIdx.x & 63;
  const int wid = threadIdx.x >> 6;  // 0..7
  const int b = blockIdx.x;

  for (int i = threadIdx.x; i < 128 * OUT_F; i += 512) acc[i] = 0.f;
  __syncthreads();

  const int beg = bstart[b];
  const int end = bstart[b + 1];
  const int cnt = end - beg;
  const int L = (cnt + 7) >> 3;       // per-wave contiguous chunk
  int e = beg + wid * L;
  const int we = min(e + L, end);

  for (; e + 3 < we; e += 4) {
    const int4 p0 = part[e + 0];
    const int4 p1 = part[e + 1];
    const int4 p2 = part[e + 2];
    const int4 p3 = part[e + 3];
    const float v0 = bf2f(support[(size_t)p0.x * OUT_F + o]);
    const float v1 = bf2f(support[(size_t)p1.x * OUT_F + o]);
    const float v2 = bf2f(support[(size_t)p2.x * OUT_F + o]);
    const float v3 = bf2f(support[(size_t)p3.x * OUT_F + o]);
    atomicAdd(&acc[((p0.z & 127) << 6) + o], v0 * __int_as_float(p0.y));
    atomicAdd(&acc[((p1.z & 127) << 6) + o], v1 * __int_as_float(p1.y));
    atomicAdd(&acc[((p2.z & 127) << 6) + o], v2 * __int_as_float(p2.y));
    atomicAdd(&acc[((p3.z & 127) << 6) + o], v3 * __int_as_float(p3.y));
  }
  for (; e < we; ++e) {
    const int4 p = part[e];
    const float v = bf2f(support[(size_t)p.x * OUT_F + o]);
    atomicAdd(&acc[((p.z & 127) << 6) + o], v * __int_as_float(p.y));
  }
  __syncthreads();

  const float bi = bias[o];
  const float ga = gamma[o];
  const float be = beta[o];
  for (int j = wid; j < 128; j += 8) {
    const int n = (b << BUCKET_SHIFT) + j;
    if (n >= N_NODES) break;
    const float v = acc[(j << 6) + o] + bi;
    float s = v, sq = v * v;
#pragma unroll
    for (int off = 32; off > 0; off >>= 1) {
      s += __shfl_xor(s, off, 64);
      sq += __shfl_xor(sq, off, 64);
    }
    const float mu = s * (1.f / 64.f);
    const float var = sq * (1.f / 64.f) - mu * mu;
    const float r = rsqrtf(var + LN_EPS);
    const float nrm = fmaxf((v - mu) * r * ga + be, 0.f);
    out[(size_t)n * OUT_F + o] = nrm + resid[(size_t)n * OUT_F + o];
  }
}

// ---------------------------------------------------------------------------
extern "C" void kernel_launch(void* const* d_in, const int* in_sizes, int n_in,
                              void* d_out, int out_size, void* d_ws,
                              size_t ws_size, hipStream_t stream) {
  const float* x      = (const float*)d_in[0];
  const float* weight = (const float*)d_in[1];
  const float* bias   = (const float*)d_in[2];
  const float* gamma  = (const float*)d_in[3];
  const float* beta   = (const float*)d_in[4];
  const float* res_w  = (const float*)d_in[5];
  const float* res_b  = (const float*)d_in[6];
  const float* ew     = (const float*)d_in[7];
  const int*   esrc   = (const int*)d_in[8];
  const int*   edst   = (const int*)d_in[9];
  float* out = (float*)d_out;

  char* ws = (char*)d_ws;
  size_t off = 0;
  auto alloc = [&](size_t bytes) {
    void* p = ws + off;
    off += (bytes + 255) & ~(size_t)255;
    return p;
  };
  unsigned short* support = (unsigned short*)alloc((size_t)N_NODES * OUT_F * 2); // 12.8MB
  float* resid   = (float*)alloc((size_t)N_NODES * OUT_F * sizeof(float));       // 25.6MB
  int4*  part    = (int4*)alloc((size_t)N_EDGES * sizeof(int4));                 // 25.6MB
  int*   bcnt    = (int*)alloc((size_t)NB * sizeof(int));
  int*   gcur    = (int*)alloc((size_t)NB * sizeof(int));
  int*   bstart  = (int*)alloc((size_t)(NB + 1) * sizeof(int));

  hipMemsetAsync(bcnt, 0, (size_t)NB * sizeof(int), stream);

  dual_gemm<<<1024, 256, 0, stream>>>(x, weight, res_w, res_b, support, resid);
  bucket_hist<<<256, 256, 0, stream>>>(edst, bcnt);
  bucket_scan<<<1, 1024, 0, stream>>>(bcnt, gcur, bstart);
  partition<<<PART_BLOCKS, PART_THREADS, 0, stream>>>(esrc, edst, ew, gcur, part);
  bucket_accum<<<NB, 512, 0, stream>>>(support, part, bstart, resid,
                                       bias, gamma, beta, out);
}